// Round 1
// baseline (11261.546 us; speedup 1.0000x reference)
//
#include <hip/hip_runtime.h>
#include <math.h>

#define N_NODES 100000
#define N_EDGES 1600000
#define F_IN 15
#define F_HID 64

// ---------------- prelude: degree / norm ----------------

__global__ void k_init_deg(float* __restrict__ deg) {
    int i = blockIdx.x * blockDim.x + threadIdx.x;
    if (i < N_NODES) deg[i] = 1.0f;  // self-loop weight
}

__global__ void k_deg_accum(const int* __restrict__ dst, const float* __restrict__ w,
                            float* __restrict__ deg) {
    int i = blockIdx.x * blockDim.x + threadIdx.x;
    if (i < N_EDGES) atomicAdd(&deg[dst[i]], w[i]);
}

__global__ void k_dinv(float* __restrict__ deg) {
    int i = blockIdx.x * blockDim.x + threadIdx.x;
    if (i < N_NODES) deg[i] = rsqrtf(deg[i]);  // deg >= 1 always
}

__global__ void k_norm(const int* __restrict__ src, const int* __restrict__ dst,
                       const float* __restrict__ w, const float* __restrict__ dinv,
                       float* __restrict__ norm) {
    int i = blockIdx.x * blockDim.x + threadIdx.x;
    if (i < N_EDGES) norm[i] = dinv[src[i]] * w[i] * dinv[dst[i]];
}

// ---------------- dense transforms ----------------

// layer 0: [N,15] @ [15,64] -> [N,64], no activation on input
__global__ void k_gemm0(const float* __restrict__ x, const float* __restrict__ W,
                        float* __restrict__ out) {
    __shared__ float Ws[F_IN * 64];
    int t = threadIdx.x;
    for (int i = t; i < F_IN * 64; i += 256) Ws[i] = W[i];
    __syncthreads();
    int r = blockIdx.x * 4 + (t >> 6);
    int c = t & 63;
    if (r < N_NODES) {
        const float* xr = x + (long)r * F_IN;
        float acc = 0.f;
#pragma unroll
        for (int k = 0; k < F_IN; k++) acc += xr[k] * Ws[k * 64 + c];
        out[(long)r * 64 + c] = acc;
    }
}

// mid/last: [N,64] @ [64,64] -> [N,64], optional relu applied to INPUT on load
template <bool RELU>
__global__ void k_gemm64(const float* __restrict__ h, const float* __restrict__ W,
                         float* __restrict__ out) {
    __shared__ float Ws[64 * 64];
    __shared__ float Hs[64 * 64];
    int t = threadIdx.x;
    const float4* W4 = (const float4*)W;
    float4* Ws4 = (float4*)Ws;
    for (int i = t; i < 64 * 16; i += 256) Ws4[i] = W4[i];

    int row0 = blockIdx.x * 64;
    int rows = N_NODES - row0; if (rows > 64) rows = 64;
    const float4* H4 = (const float4*)(h + (long)row0 * 64);
    float4* Hs4 = (float4*)Hs;
    for (int i = t; i < rows * 16; i += 256) {
        float4 v = H4[i];
        if (RELU) {
            v.x = fmaxf(v.x, 0.f); v.y = fmaxf(v.y, 0.f);
            v.z = fmaxf(v.z, 0.f); v.w = fmaxf(v.w, 0.f);
        }
        Hs4[i] = v;
    }
    __syncthreads();

    int g = t >> 6;   // wave-uniform row-group
    int c = t & 63;
    float acc[16];
#pragma unroll
    for (int j = 0; j < 16; j++) acc[j] = 0.f;
    for (int k = 0; k < 64; k++) {
        float wv = Ws[k * 64 + c];       // stride-1 across lanes: conflict-free
#pragma unroll
        for (int j = 0; j < 16; j++)
            acc[j] += Hs[(g + 4 * j) * 64 + k] * wv;  // wave-uniform: LDS broadcast
    }
#pragma unroll
    for (int j = 0; j < 16; j++) {
        int r = g + 4 * j;
        if (r < rows) out[(long)(row0 + r) * 64 + c] = acc[j];
    }
}

// ---------------- aggregation ----------------

// out[i] = b + dinv[i]^2 * htmp[i]   (self-loop term + bias), vectorized float4
__global__ void k_aggr_init(const float* __restrict__ htmp, const float* __restrict__ dinv,
                            const float* __restrict__ b, float* __restrict__ out) {
    int i = blockIdx.x * blockDim.x + threadIdx.x;  // over N*16 float4 slots
    if (i >= N_NODES * 16) return;
    int node = i >> 4, q = i & 15;
    float4 v = ((const float4*)htmp)[i];
    float dv = dinv[node];
    float sn = dv * dv;
    float4 bv = ((const float4*)b)[q];
    float4 o;
    o.x = bv.x + sn * v.x; o.y = bv.y + sn * v.y;
    o.z = bv.z + sn * v.z; o.w = bv.w + sn * v.w;
    ((float4*)out)[i] = o;
}

// out[dst] += norm * htmp[src], 16 lanes (4 feats each) per edge
__global__ void k_scatter(const int* __restrict__ src, const int* __restrict__ dst,
                          const float* __restrict__ norm, const float* __restrict__ htmp,
                          float* __restrict__ out) {
    long i = (long)blockIdx.x * blockDim.x + threadIdx.x;  // over E*16
    if (i >= (long)N_EDGES * 16) return;
    int e = (int)(i >> 4), q = (int)(i & 15);
    int s = src[e], d = dst[e];
    float nm = norm[e];
    float4 v = ((const float4*)htmp)[s * 16 + q];
    float* op = out + (long)d * 64 + q * 4;
    atomicAdd(op + 0, nm * v.x);
    atomicAdd(op + 1, nm * v.y);
    atomicAdd(op + 2, nm * v.z);
    atomicAdd(op + 3, nm * v.w);
}

__global__ void k_sigmoid(float* __restrict__ out) {
    int i = blockIdx.x * blockDim.x + threadIdx.x;  // over N*16 float4
    if (i >= N_NODES * 16) return;
    float4 v = ((float4*)out)[i];
    v.x = 1.0f / (1.0f + expf(-v.x));
    v.y = 1.0f / (1.0f + expf(-v.y));
    v.z = 1.0f / (1.0f + expf(-v.z));
    v.w = 1.0f / (1.0f + expf(-v.w));
    ((float4*)out)[i] = v;
}

// ---------------- launch ----------------

extern "C" void kernel_launch(void* const* d_in, const int* in_sizes, int n_in,
                              void* d_out, int out_size, void* d_ws, size_t ws_size,
                              hipStream_t stream) {
    const float* x  = (const float*)d_in[0];
    const int*   ei = (const int*)  d_in[1];
    const float* ew = (const float*)d_in[2];
    const float* W0 = (const float*)d_in[3];
    const float* b0 = (const float*)d_in[4];
    const float* Wm = (const float*)d_in[5];
    const float* bm = (const float*)d_in[6];
    const float* Wl = (const float*)d_in[7];
    const float* bl = (const float*)d_in[8];
    float* out = (float*)d_out;

    const int* src = ei;
    const int* dst = ei + N_EDGES;

    char* ws = (char*)d_ws;
    float* deg  = (float*)(ws + 0);               // N floats (becomes dinv in-place)
    float* norm = (float*)(ws + (1u << 20));      // E floats = 6.4 MB
    float* htmp = (float*)(ws + (8u << 20));      // N*64 = 25.6 MB
    float* hA   = (float*)(ws + (40u << 20));     // 25.6 MB
    float* hB   = (float*)(ws + (72u << 20));     // 25.6 MB

    const int BT = 256;
    dim3 blk(BT);
    int gN   = (N_NODES + BT - 1) / BT;              // 391
    int gE   = (N_EDGES + BT - 1) / BT;              // 6250
    int gN16 = (N_NODES * 16 + BT - 1) / BT;         // 6250
    long e16 = (long)N_EDGES * 16;
    int gE16 = (int)((e16 + BT - 1) / BT);           // 100000
    int gRow = (N_NODES + 63) / 64;                  // 1563
    int gR4  = (N_NODES + 3) / 4;                    // 25000

    // prelude
    hipLaunchKernelGGL(k_init_deg,  dim3(gN),  blk, 0, stream, deg);
    hipLaunchKernelGGL(k_deg_accum, dim3(gE),  blk, 0, stream, dst, ew, deg);
    hipLaunchKernelGGL(k_dinv,      dim3(gN),  blk, 0, stream, deg);
    hipLaunchKernelGGL(k_norm,      dim3(gE),  blk, 0, stream, src, dst, ew, deg, norm);

    // layer 0
    hipLaunchKernelGGL(k_gemm0,     dim3(gR4), blk, 0, stream, x, W0, htmp);
    hipLaunchKernelGGL(k_aggr_init, dim3(gN16),blk, 0, stream, htmp, deg, b0, hA);
    hipLaunchKernelGGL(k_scatter,   dim3(gE16),blk, 0, stream, src, dst, norm, htmp, hA);

    // middle layers 1..6 (relu fused into gemm input load)
    float* hin = hA;
    float* hout = hB;
    for (int i = 0; i < 6; i++) {
        const float* Wi = Wm + (long)i * 64 * 64;
        const float* bi = bm + (long)i * 64;
        hipLaunchKernelGGL((k_gemm64<true>), dim3(gRow), blk, 0, stream, hin, Wi, htmp);
        hipLaunchKernelGGL(k_aggr_init, dim3(gN16), blk, 0, stream, htmp, deg, bi, hout);
        hipLaunchKernelGGL(k_scatter,   dim3(gE16), blk, 0, stream, src, dst, norm, htmp, hout);
        float* t2 = hin; hin = hout; hout = t2;
    }

    // final layer + sigmoid, aggregate straight into d_out
    hipLaunchKernelGGL((k_gemm64<true>), dim3(gRow), blk, 0, stream, hin, Wl, htmp);
    hipLaunchKernelGGL(k_aggr_init, dim3(gN16), blk, 0, stream, htmp, deg, bl, out);
    hipLaunchKernelGGL(k_scatter,   dim3(gE16), blk, 0, stream, src, dst, norm, htmp, out);
    hipLaunchKernelGGL(k_sigmoid,   dim3(gN16), blk, 0, stream, out);
}

// Round 2
// 1333.426 us; speedup vs baseline: 8.4456x; 8.4456x over previous
//
#include <hip/hip_runtime.h>
#include <math.h>

#define N_NODES 100000
#define N_EDGES 1600000
#define F_IN 15
#define F_HID 64

// ---------------- prelude: degree / count ----------------

__global__ void k_init(float* __restrict__ deg, int* __restrict__ cnt) {
    int i = blockIdx.x * blockDim.x + threadIdx.x;
    if (i < N_NODES) { deg[i] = 1.0f; cnt[i] = 0; }  // self-loop weight
}

__global__ void k_deg_cnt(const int* __restrict__ dst, const float* __restrict__ w,
                          float* __restrict__ deg, int* __restrict__ cnt) {
    int i = blockIdx.x * blockDim.x + threadIdx.x;
    if (i < N_EDGES) {
        int d = dst[i];
        atomicAdd(&deg[d], w[i]);
        atomicAdd(&cnt[d], 1);
    }
}

__global__ void k_dinv(float* __restrict__ deg) {
    int i = blockIdx.x * blockDim.x + threadIdx.x;
    if (i < N_NODES) deg[i] = rsqrtf(deg[i]);  // deg >= 1 always (self-loop)
}

// single-block exclusive scan of cnt -> rowptr (and cursor copy)
__global__ __launch_bounds__(1024) void k_scan(const int* __restrict__ cnt,
                                               int* __restrict__ rowptr,
                                               int* __restrict__ cursor) {
    __shared__ int part[1024];
    int t = threadIdx.x;
    const int CH = (N_NODES + 1023) / 1024;  // 98
    int lo = t * CH, hi = lo + CH;
    if (hi > N_NODES) hi = N_NODES;
    int s = 0;
    for (int i = lo; i < hi; i++) s += cnt[i];
    part[t] = s;
    __syncthreads();
    for (int off = 1; off < 1024; off <<= 1) {
        int u = (t >= off) ? part[t - off] : 0;
        __syncthreads();
        part[t] += u;
        __syncthreads();
    }
    int run = part[t] - s;  // exclusive prefix of this chunk
    for (int i = lo; i < hi; i++) {
        rowptr[i] = run; cursor[i] = run;
        run += cnt[i];
    }
    if (t == 0) rowptr[N_NODES] = part[1023];  // == N_EDGES
}

// scatter edges into CSR slots; record = (src, norm)
__global__ void k_fill(const int* __restrict__ src, const int* __restrict__ dst,
                       const float* __restrict__ w, const float* __restrict__ dinv,
                       int* __restrict__ cursor, int2* __restrict__ csr) {
    int i = blockIdx.x * blockDim.x + threadIdx.x;
    if (i >= N_EDGES) return;
    int s = src[i], d = dst[i];
    float nm = dinv[s] * w[i] * dinv[d];
    int pos = atomicAdd(&cursor[d], 1);
    csr[pos] = make_int2(s, __float_as_int(nm));
}

// ---------------- dense transforms ----------------

// layer 0: [N,15] @ [15,64] -> [N,64]
__global__ void k_gemm0(const float* __restrict__ x, const float* __restrict__ W,
                        float* __restrict__ out) {
    __shared__ float Ws[F_IN * 64];
    int t = threadIdx.x;
    for (int i = t; i < F_IN * 64; i += 256) Ws[i] = W[i];
    __syncthreads();
    int r = blockIdx.x * 4 + (t >> 6);
    int c = t & 63;
    if (r < N_NODES) {
        const float* xr = x + (long)r * F_IN;
        float acc = 0.f;
#pragma unroll
        for (int k = 0; k < F_IN; k++) acc += xr[k] * Ws[k * 64 + c];
        out[(long)r * 64 + c] = acc;
    }
}

// mid/last: [N,64] @ [64,64] -> [N,64], relu applied to INPUT on load
template <bool RELU>
__global__ void k_gemm64(const float* __restrict__ h, const float* __restrict__ W,
                         float* __restrict__ out) {
    __shared__ float Ws[64 * 64];
    __shared__ float Hs[64 * 64];
    int t = threadIdx.x;
    const float4* W4 = (const float4*)W;
    float4* Ws4 = (float4*)Ws;
    for (int i = t; i < 64 * 16; i += 256) Ws4[i] = W4[i];

    int row0 = blockIdx.x * 64;
    int rows = N_NODES - row0; if (rows > 64) rows = 64;
    const float4* H4 = (const float4*)(h + (long)row0 * 64);
    float4* Hs4 = (float4*)Hs;
    for (int i = t; i < rows * 16; i += 256) {
        float4 v = H4[i];
        if (RELU) {
            v.x = fmaxf(v.x, 0.f); v.y = fmaxf(v.y, 0.f);
            v.z = fmaxf(v.z, 0.f); v.w = fmaxf(v.w, 0.f);
        }
        Hs4[i] = v;
    }
    __syncthreads();

    int g = t >> 6;   // wave-uniform row-group
    int c = t & 63;
    float acc[16];
#pragma unroll
    for (int j = 0; j < 16; j++) acc[j] = 0.f;
    for (int k = 0; k < 64; k++) {
        float wv = Ws[k * 64 + c];       // stride-1 across lanes: conflict-free
#pragma unroll
        for (int j = 0; j < 16; j++)
            acc[j] += Hs[(g + 4 * j) * 64 + k] * wv;  // wave-uniform: LDS broadcast
    }
#pragma unroll
    for (int j = 0; j < 16; j++) {
        int r = g + 4 * j;
        if (r < rows) out[(long)(row0 + r) * 64 + c] = acc[j];
    }
}

// ---------------- aggregation: one wave per node, lane = feature ----------------

template <bool SIG>
__global__ void k_gather(const int* __restrict__ rowptr, const int2* __restrict__ csr,
                         const float* __restrict__ htmp, const float* __restrict__ dinv,
                         const float* __restrict__ b, float* __restrict__ out) {
    int n = (blockIdx.x * blockDim.x + threadIdx.x) >> 6;
    int lane = threadIdx.x & 63;
    if (n >= N_NODES) return;
    int e0 = rowptr[n], e1 = rowptr[n + 1];
    float dv = dinv[n];
    float acc = dv * dv * htmp[(long)n * 64 + lane];  // self-loop term
    int e = e0;
    for (; e + 4 <= e1; e += 4) {
        int2 r0 = csr[e], r1 = csr[e + 1], r2 = csr[e + 2], r3 = csr[e + 3];
        float h0 = htmp[(long)r0.x * 64 + lane];
        float h1 = htmp[(long)r1.x * 64 + lane];
        float h2 = htmp[(long)r2.x * 64 + lane];
        float h3 = htmp[(long)r3.x * 64 + lane];
        acc += __int_as_float(r0.y) * h0;
        acc += __int_as_float(r1.y) * h1;
        acc += __int_as_float(r2.y) * h2;
        acc += __int_as_float(r3.y) * h3;
    }
    for (; e < e1; e++) {
        int2 r = csr[e];
        acc += __int_as_float(r.y) * htmp[(long)r.x * 64 + lane];
    }
    acc += b[lane];
    if (SIG) acc = 1.0f / (1.0f + expf(-acc));
    out[(long)n * 64 + lane] = acc;
}

// ---------------- launch ----------------

extern "C" void kernel_launch(void* const* d_in, const int* in_sizes, int n_in,
                              void* d_out, int out_size, void* d_ws, size_t ws_size,
                              hipStream_t stream) {
    const float* x  = (const float*)d_in[0];
    const int*   ei = (const int*)  d_in[1];
    const float* ew = (const float*)d_in[2];
    const float* W0 = (const float*)d_in[3];
    const float* b0 = (const float*)d_in[4];
    const float* Wm = (const float*)d_in[5];
    const float* bm = (const float*)d_in[6];
    const float* Wl = (const float*)d_in[7];
    const float* bl = (const float*)d_in[8];
    float* out = (float*)d_out;

    const int* src = ei;
    const int* dst = ei + N_EDGES;

    char* ws = (char*)d_ws;
    float* deg    = (float*)(ws + 0);              // N floats (becomes dinv)
    int*   cnt    = (int*)  (ws + (1u  << 20));    // N ints
    int*   rowptr = (int*)  (ws + (2u  << 20));    // N+1 ints
    int*   cursor = (int*)  (ws + (3u  << 20));    // N ints
    int2*  csr    = (int2*) (ws + (4u  << 20));    // E * 8B = 12.8 MB
    float* htmp   = (float*)(ws + (18u << 20));    // N*64 = 25.6 MB
    float* hA     = (float*)(ws + (44u << 20));    // 25.6 MB
    float* hB     = (float*)(ws + (70u << 20));    // 25.6 MB

    const int BT = 256;
    dim3 blk(BT);
    int gN   = (N_NODES + BT - 1) / BT;        // 391
    int gE   = (N_EDGES + BT - 1) / BT;        // 6250
    int gRow = (N_NODES + 63) / 64;            // 1563 (gemm64 blocks)
    int gR4  = (N_NODES + 3) / 4;              // 25000 (gemm0 blocks)
    int gW   = (N_NODES * 64 + BT - 1) / BT;   // 25000 (gather: 1 wave/node)

    // prelude: degree, counts, scan, CSR fill
    hipLaunchKernelGGL(k_init,    dim3(gN), blk, 0, stream, deg, cnt);
    hipLaunchKernelGGL(k_deg_cnt, dim3(gE), blk, 0, stream, dst, ew, deg, cnt);
    hipLaunchKernelGGL(k_dinv,    dim3(gN), blk, 0, stream, deg);
    hipLaunchKernelGGL(k_scan,    dim3(1), dim3(1024), 0, stream, cnt, rowptr, cursor);
    hipLaunchKernelGGL(k_fill,    dim3(gE), blk, 0, stream, src, dst, ew, deg, cursor, csr);

    // layer 0
    hipLaunchKernelGGL(k_gemm0,          dim3(gR4),  blk, 0, stream, x, W0, htmp);
    hipLaunchKernelGGL((k_gather<false>),dim3(gW),   blk, 0, stream, rowptr, csr, htmp, deg, b0, hA);

    // middle layers 1..6 (relu fused into gemm input load)
    float* hin = hA;
    float* hout = hB;
    for (int i = 0; i < 6; i++) {
        const float* Wi = Wm + (long)i * 64 * 64;
        const float* bi = bm + (long)i * 64;
        hipLaunchKernelGGL((k_gemm64<true>),  dim3(gRow), blk, 0, stream, hin, Wi, htmp);
        hipLaunchKernelGGL((k_gather<false>), dim3(gW),   blk, 0, stream, rowptr, csr, htmp, deg, bi, hout);
        float* t2 = hin; hin = hout; hout = t2;
    }

    // final layer: aggregate + sigmoid straight into d_out
    hipLaunchKernelGGL((k_gemm64<true>),  dim3(gRow), blk, 0, stream, hin, Wl, htmp);
    hipLaunchKernelGGL((k_gather<true>),  dim3(gW),   blk, 0, stream, rowptr, csr, htmp, deg, bl, out);
}

// Round 3
// 1114.020 us; speedup vs baseline: 10.1089x; 1.1969x over previous
//
#include <hip/hip_runtime.h>
#include <math.h>

#define N_NODES 100000
#define N_EDGES 1600000
#define F_IN 15
#define F_HID 64
#define NB_NODES 391   // ceil(N_NODES/256)

// ---------------- prelude: degree / count ----------------

__global__ void k_init(float* __restrict__ deg, int* __restrict__ cnt) {
    int i = blockIdx.x * blockDim.x + threadIdx.x;
    if (i < N_NODES) { deg[i] = 1.0f; cnt[i] = 0; }  // self-loop weight
}

__global__ void k_deg_cnt(const int* __restrict__ dst, const float* __restrict__ w,
                          float* __restrict__ deg, int* __restrict__ cnt) {
    int i = blockIdx.x * blockDim.x + threadIdx.x;
    if (i < N_EDGES) {
        int d = dst[i];
        atomicAdd(&deg[d], w[i]);
        atomicAdd(&cnt[d], 1);
    }
}

// phase A: per-block sum of cnt -> bsum[block]; fused deg -> rsqrt(deg)
__global__ void k_part(const int* __restrict__ cnt, int* __restrict__ bsum,
                       float* __restrict__ deg) {
    __shared__ int red[256];
    int t = threadIdx.x;
    int i = blockIdx.x * 256 + t;
    int v = (i < N_NODES) ? cnt[i] : 0;
    if (i < N_NODES) deg[i] = rsqrtf(deg[i]);  // deg >= 1 (self-loop)
    red[t] = v;
    __syncthreads();
    for (int off = 128; off > 0; off >>= 1) {
        if (t < off) red[t] += red[t + off];
        __syncthreads();
    }
    if (t == 0) bsum[blockIdx.x] = red[0];
}

// phase B: single-block exclusive scan of bsum[NB_NODES] (NB_NODES <= 512)
__global__ __launch_bounds__(512) void k_scanb(int* __restrict__ bsum,
                                               int* __restrict__ rowptr) {
    __shared__ int sc[512];
    int t = threadIdx.x;
    int v = (t < NB_NODES) ? bsum[t] : 0;
    sc[t] = v;
    __syncthreads();
    for (int off = 1; off < 512; off <<= 1) {
        int u = (t >= off) ? sc[t - off] : 0;
        __syncthreads();
        sc[t] += u;
        __syncthreads();
    }
    if (t < NB_NODES) bsum[t] = sc[t] - v;  // exclusive
    if (t == 0) rowptr[N_NODES] = N_EDGES;  // total augmented count is constant
}

// phase C: in-block exclusive scan of cnt + block offset -> rowptr, cursor
__global__ void k_fillptr(const int* __restrict__ cnt, const int* __restrict__ bsum,
                          int* __restrict__ rowptr, int* __restrict__ cursor) {
    __shared__ int sc[256];
    int t = threadIdx.x;
    int i = blockIdx.x * 256 + t;
    int v = (i < N_NODES) ? cnt[i] : 0;
    sc[t] = v;
    __syncthreads();
    for (int off = 1; off < 256; off <<= 1) {
        int u = (t >= off) ? sc[t - off] : 0;
        __syncthreads();
        sc[t] += u;
        __syncthreads();
    }
    if (i < N_NODES) {
        int p = bsum[blockIdx.x] + sc[t] - v;  // exclusive prefix
        rowptr[i] = p;
        cursor[i] = p;
    }
}

// scatter edges into CSR slots; record = (src, norm)
__global__ void k_fill(const int* __restrict__ src, const int* __restrict__ dst,
                       const float* __restrict__ w, const float* __restrict__ dinv,
                       int* __restrict__ cursor, int2* __restrict__ csr) {
    int i = blockIdx.x * blockDim.x + threadIdx.x;
    if (i >= N_EDGES) return;
    int s = src[i], d = dst[i];
    float nm = dinv[s] * w[i] * dinv[d];
    int pos = atomicAdd(&cursor[d], 1);
    csr[pos] = make_int2(s, __float_as_int(nm));
}

// ---------------- dense transforms ----------------

// layer 0: [N,15] @ [15,64] -> [N,64]
__global__ void k_gemm0(const float* __restrict__ x, const float* __restrict__ W,
                        float* __restrict__ out) {
    __shared__ float Ws[F_IN * 64];
    int t = threadIdx.x;
    for (int i = t; i < F_IN * 64; i += 256) Ws[i] = W[i];
    __syncthreads();
    int r = blockIdx.x * 4 + (t >> 6);
    int c = t & 63;
    if (r < N_NODES) {
        const float* xr = x + (long)r * F_IN;
        float acc = 0.f;
#pragma unroll
        for (int k = 0; k < F_IN; k++) acc += xr[k] * Ws[k * 64 + c];
        out[(long)r * 64 + c] = acc;
    }
}

// mid/last: [N,64] @ [64,64] -> [N,64], relu applied to INPUT on load
template <bool RELU>
__global__ void k_gemm64(const float* __restrict__ h, const float* __restrict__ W,
                         float* __restrict__ out) {
    __shared__ float Ws[64 * 64];
    __shared__ float Hs[64 * 64];
    int t = threadIdx.x;
    const float4* W4 = (const float4*)W;
    float4* Ws4 = (float4*)Ws;
    for (int i = t; i < 64 * 16; i += 256) Ws4[i] = W4[i];

    int row0 = blockIdx.x * 64;
    int rows = N_NODES - row0; if (rows > 64) rows = 64;
    const float4* H4 = (const float4*)(h + (long)row0 * 64);
    float4* Hs4 = (float4*)Hs;
    for (int i = t; i < rows * 16; i += 256) {
        float4 v = H4[i];
        if (RELU) {
            v.x = fmaxf(v.x, 0.f); v.y = fmaxf(v.y, 0.f);
            v.z = fmaxf(v.z, 0.f); v.w = fmaxf(v.w, 0.f);
        }
        Hs4[i] = v;
    }
    __syncthreads();

    int g = t >> 6;   // wave-uniform row-group
    int c = t & 63;
    float acc[16];
#pragma unroll
    for (int j = 0; j < 16; j++) acc[j] = 0.f;
    for (int k = 0; k < 64; k++) {
        float wv = Ws[k * 64 + c];       // stride-1 across lanes: conflict-free
#pragma unroll
        for (int j = 0; j < 16; j++)
            acc[j] += Hs[(g + 4 * j) * 64 + k] * wv;  // wave-uniform: LDS broadcast
    }
#pragma unroll
    for (int j = 0; j < 16; j++) {
        int r = g + 4 * j;
        if (r < rows) out[(long)(row0 + r) * 64 + c] = acc[j];
    }
}

// ---------------- aggregation: one wave per node, lane = feature ----------------

template <bool SIG>
__global__ void k_gather(const int* __restrict__ rowptr, const int2* __restrict__ csr,
                         const float* __restrict__ htmp, const float* __restrict__ dinv,
                         const float* __restrict__ b, float* __restrict__ out) {
    int n = (blockIdx.x * blockDim.x + threadIdx.x) >> 6;
    int lane = threadIdx.x & 63;
    if (n >= N_NODES) return;
    int e0 = rowptr[n], e1 = rowptr[n + 1];
    float dv = dinv[n];
    float acc = dv * dv * htmp[(long)n * 64 + lane];  // self-loop term
    int e = e0;
    for (; e + 4 <= e1; e += 4) {
        int2 r0 = csr[e], r1 = csr[e + 1], r2 = csr[e + 2], r3 = csr[e + 3];
        float h0 = htmp[(long)r0.x * 64 + lane];
        float h1 = htmp[(long)r1.x * 64 + lane];
        float h2 = htmp[(long)r2.x * 64 + lane];
        float h3 = htmp[(long)r3.x * 64 + lane];
        acc += __int_as_float(r0.y) * h0;
        acc += __int_as_float(r1.y) * h1;
        acc += __int_as_float(r2.y) * h2;
        acc += __int_as_float(r3.y) * h3;
    }
    for (; e < e1; e++) {
        int2 r = csr[e];
        acc += __int_as_float(r.y) * htmp[(long)r.x * 64 + lane];
    }
    acc += b[lane];
    if (SIG) acc = 1.0f / (1.0f + expf(-acc));
    out[(long)n * 64 + lane] = acc;
}

// ---------------- launch ----------------

extern "C" void kernel_launch(void* const* d_in, const int* in_sizes, int n_in,
                              void* d_out, int out_size, void* d_ws, size_t ws_size,
                              hipStream_t stream) {
    const float* x  = (const float*)d_in[0];
    const int*   ei = (const int*)  d_in[1];
    const float* ew = (const float*)d_in[2];
    const float* W0 = (const float*)d_in[3];
    const float* b0 = (const float*)d_in[4];
    const float* Wm = (const float*)d_in[5];
    const float* bm = (const float*)d_in[6];
    const float* Wl = (const float*)d_in[7];
    const float* bl = (const float*)d_in[8];
    float* out = (float*)d_out;

    const int* src = ei;
    const int* dst = ei + N_EDGES;

    char* ws = (char*)d_ws;
    float* deg    = (float*)(ws + 0);              // N floats (becomes dinv)
    int*   cnt    = (int*)  (ws + (1u  << 20));    // N ints
    int*   rowptr = (int*)  (ws + (2u  << 20));    // N+1 ints
    int*   cursor = (int*)  (ws + (3u  << 20));    // N ints
    int*   bsum   = (int*)  (ws + (3u  << 20) + 512 * 1024);  // NB_NODES ints
    int2*  csr    = (int2*) (ws + (4u  << 20));    // E * 8B = 12.8 MB
    float* htmp   = (float*)(ws + (18u << 20));    // N*64 = 25.6 MB
    float* hA     = (float*)(ws + (44u << 20));    // 25.6 MB
    float* hB     = (float*)(ws + (70u << 20));    // 25.6 MB

    const int BT = 256;
    dim3 blk(BT);
    int gN   = NB_NODES;                       // 391
    int gE   = (N_EDGES + BT - 1) / BT;        // 6250
    int gRow = (N_NODES + 63) / 64;            // 1563 (gemm64 blocks)
    int gR4  = (N_NODES + 3) / 4;              // 25000 (gemm0 blocks)
    int gW   = (N_NODES * 64 + BT - 1) / BT;   // 25000 (gather: 1 wave/node)

    // prelude: degree, counts, 3-phase scan, CSR fill
    hipLaunchKernelGGL(k_init,    dim3(gN), blk, 0, stream, deg, cnt);
    hipLaunchKernelGGL(k_deg_cnt, dim3(gE), blk, 0, stream, dst, ew, deg, cnt);
    hipLaunchKernelGGL(k_part,    dim3(gN), blk, 0, stream, cnt, bsum, deg);
    hipLaunchKernelGGL(k_scanb,   dim3(1), dim3(512), 0, stream, bsum, rowptr);
    hipLaunchKernelGGL(k_fillptr, dim3(gN), blk, 0, stream, cnt, bsum, rowptr, cursor);
    hipLaunchKernelGGL(k_fill,    dim3(gE), blk, 0, stream, src, dst, ew, deg, cursor, csr);

    // layer 0
    hipLaunchKernelGGL(k_gemm0,          dim3(gR4),  blk, 0, stream, x, W0, htmp);
    hipLaunchKernelGGL((k_gather<false>),dim3(gW),   blk, 0, stream, rowptr, csr, htmp, deg, b0, hA);

    // middle layers 1..6 (relu fused into gemm input load)
    float* hin = hA;
    float* hout = hB;
    for (int i = 0; i < 6; i++) {
        const float* Wi = Wm + (long)i * 64 * 64;
        const float* bi = bm + (long)i * 64;
        hipLaunchKernelGGL((k_gemm64<true>),  dim3(gRow), blk, 0, stream, hin, Wi, htmp);
        hipLaunchKernelGGL((k_gather<false>), dim3(gW),   blk, 0, stream, rowptr, csr, htmp, deg, bi, hout);
        float* t2 = hin; hin = hout; hout = t2;
    }

    // final layer: aggregate + sigmoid straight into d_out
    hipLaunchKernelGGL((k_gemm64<true>),  dim3(gRow), blk, 0, stream, hin, Wl, htmp);
    hipLaunchKernelGGL((k_gather<true>),  dim3(gW),   blk, 0, stream, rowptr, csr, htmp, deg, bl, out);
}

// Round 4
// 730.023 us; speedup vs baseline: 15.4263x; 1.5260x over previous
//
#include <hip/hip_runtime.h>
#include <hip/hip_fp16.h>
#include <math.h>

#define N_NODES 100000
#define N_EDGES 1600000
#define F_IN 15
#define NB_NODES 391   // ceil(N_NODES/256)
#define MASK40 ((1ull << 40) - 1)

// ---------------- prelude ----------------

__global__ void k_initp(unsigned long long* __restrict__ packed) {
    int i = blockIdx.x * blockDim.x + threadIdx.x;
    if (i < N_NODES) packed[i] = 0ull;
}

// one packed 64-bit atomic per edge: count in bits [40..], weight-sum as 32.8
// fixed point in bits [0..40). Returned old count = this edge's CSR ordinal.
__global__ void k_cnt(const int* __restrict__ dst, const float* __restrict__ w,
                      unsigned long long* __restrict__ packed, int* __restrict__ ord) {
    int i = blockIdx.x * blockDim.x + threadIdx.x;
    if (i >= N_EDGES) return;
    int d = dst[i];
    unsigned long long contrib =
        (1ull << 40) + (unsigned long long)((double)w[i] * 4294967296.0);
    unsigned long long old = atomicAdd(&packed[d], contrib);
    ord[i] = (int)(old >> 40);
}

// per-block sum of counts -> bsum; fused dinv = rsqrt(1 + sum_w)
__global__ void k_part(const unsigned long long* __restrict__ packed,
                       int* __restrict__ bsum, float* __restrict__ dinv) {
    __shared__ int red[256];
    int t = threadIdx.x;
    int i = blockIdx.x * 256 + t;
    int c = 0;
    if (i < N_NODES) {
        unsigned long long p = packed[i];
        c = (int)(p >> 40);
        float deg = 1.0f + (float)((double)(p & MASK40) * 0x1p-32);  // + self loop
        dinv[i] = rsqrtf(deg);
    }
    red[t] = c;
    __syncthreads();
    for (int off = 128; off > 0; off >>= 1) {
        if (t < off) red[t] += red[t + off];
        __syncthreads();
    }
    if (t == 0) bsum[blockIdx.x] = red[0];
}

// single-block exclusive scan of bsum[NB_NODES]
__global__ __launch_bounds__(512) void k_scanb(int* __restrict__ bsum,
                                               int* __restrict__ rowptr) {
    __shared__ int sc[512];
    int t = threadIdx.x;
    int v = (t < NB_NODES) ? bsum[t] : 0;
    sc[t] = v;
    __syncthreads();
    for (int off = 1; off < 512; off <<= 1) {
        int u = (t >= off) ? sc[t - off] : 0;
        __syncthreads();
        sc[t] += u;
        __syncthreads();
    }
    if (t < NB_NODES) bsum[t] = sc[t] - v;  // exclusive
    if (t == 0) rowptr[N_NODES] = N_EDGES;  // total is a compile-time constant
}

// in-block exclusive scan of counts + block offset -> rowptr
__global__ void k_fillptr(const unsigned long long* __restrict__ packed,
                          const int* __restrict__ bsum, int* __restrict__ rowptr) {
    __shared__ int sc[256];
    int t = threadIdx.x;
    int i = blockIdx.x * 256 + t;
    int v = (i < N_NODES) ? (int)(packed[i] >> 40) : 0;
    sc[t] = v;
    __syncthreads();
    for (int off = 1; off < 256; off <<= 1) {
        int u = (t >= off) ? sc[t - off] : 0;
        __syncthreads();
        sc[t] += u;
        __syncthreads();
    }
    if (i < N_NODES) rowptr[i] = bsum[blockIdx.x] + sc[t] - v;
}

// atomic-free CSR fill: slot = rowptr[dst] + per-edge ordinal
__global__ void k_fill(const int* __restrict__ src, const int* __restrict__ dst,
                       const float* __restrict__ w, const float* __restrict__ dinv,
                       const int* __restrict__ rowptr, const int* __restrict__ ord,
                       int2* __restrict__ csr) {
    int i = blockIdx.x * blockDim.x + threadIdx.x;
    if (i >= N_EDGES) return;
    int s = src[i], d = dst[i];
    float nm = dinv[s] * w[i] * dinv[d];
    csr[rowptr[d] + ord[i]] = make_int2(s, __float_as_int(nm));
}

// ---------------- layer 0 dense transform ----------------

// [N,15] @ [15,64] -> [N,64] fp32
__global__ void k_gemm0(const float* __restrict__ x, const float* __restrict__ W,
                        float* __restrict__ out) {
    __shared__ float Ws[F_IN * 64];
    int t = threadIdx.x;
    for (int i = t; i < F_IN * 64; i += 256) Ws[i] = W[i];
    __syncthreads();
    int r = blockIdx.x * 4 + (t >> 6);
    int c = t & 63;
    if (r < N_NODES) {
        const float* xr = x + (long)r * F_IN;
        float acc = 0.f;
#pragma unroll
        for (int k = 0; k < F_IN; k++) acc += xr[k] * Ws[k * 64 + c];
        out[(long)r * 64 + c] = acc;
    }
}

// ---------------- layer 0 aggregation: fp32 in, fp16 out, +bias ----------------

__global__ void k_gather0(const int* __restrict__ rowptr, const int2* __restrict__ csr,
                          const float* __restrict__ htmp, const float* __restrict__ dinv,
                          const float* __restrict__ b, __half* __restrict__ out) {
    int n = (blockIdx.x * blockDim.x + threadIdx.x) >> 6;
    int lane = threadIdx.x & 63;
    if (n >= N_NODES) return;
    int e0 = __builtin_amdgcn_readfirstlane(rowptr[n]);
    int e1 = __builtin_amdgcn_readfirstlane(rowptr[n + 1]);
    float dv = dinv[n];
    float acc = dv * dv * htmp[(long)n * 64 + lane];  // self-loop (no relu: layer 0)
    int e = e0;
    for (; e + 4 <= e1; e += 4) {
        int2 r0 = csr[e], r1 = csr[e + 1], r2 = csr[e + 2], r3 = csr[e + 3];
        float h0 = htmp[(long)r0.x * 64 + lane];
        float h1 = htmp[(long)r1.x * 64 + lane];
        float h2 = htmp[(long)r2.x * 64 + lane];
        float h3 = htmp[(long)r3.x * 64 + lane];
        acc += __int_as_float(r0.y) * h0;
        acc += __int_as_float(r1.y) * h1;
        acc += __int_as_float(r2.y) * h2;
        acc += __int_as_float(r3.y) * h3;
    }
    for (; e < e1; e++) {
        int2 r = csr[e];
        acc += __int_as_float(r.y) * htmp[(long)r.x * 64 + lane];
    }
    acc += b[lane];
    out[(long)n * 64 + lane] = __float2half(acc);  // pre-relu; next layer relus on load
}

// ---------------- fused aggregation + dense: out = (A relu(hin)) W + b ----------------
// Uses (A h)W == A(hW). One wave per node, 8 nodes per wave; fp16 hidden states.

template <bool SIG>
__global__ __launch_bounds__(256) void k_gather_w(
        const int* __restrict__ rowptr, const int2* __restrict__ csr,
        const __half* __restrict__ hin, const float* __restrict__ dinv,
        const float* __restrict__ W, const float* __restrict__ b,
        void* __restrict__ outp) {
    __shared__ float Ws[64 * 64];
    __shared__ float gs[4 * 64];
    int t = threadIdx.x;
    const float4* W4 = (const float4*)W;
    float4* Ws4 = (float4*)Ws;
    for (int i = t; i < 64 * 16; i += 256) Ws4[i] = W4[i];
    __syncthreads();

    int wv = t >> 6, lane = t & 63;
    float bl = b[lane];
    float* gw = gs + wv * 64;

#pragma unroll 1
    for (int j = 0; j < 8; j++) {
        int n = blockIdx.x * 32 + j * 4 + wv;  // grid sized so n < N_NODES always
        int e0 = __builtin_amdgcn_readfirstlane(rowptr[n]);
        int e1 = __builtin_amdgcn_readfirstlane(rowptr[n + 1]);
        float dv = dinv[n];
        float acc = dv * dv * fmaxf(__half2float(hin[(long)n * 64 + lane]), 0.f);
        int e = e0;
        for (; e + 4 <= e1; e += 4) {
            int2 r0 = csr[e], r1 = csr[e + 1], r2 = csr[e + 2], r3 = csr[e + 3];
            float h0 = fmaxf(__half2float(hin[(long)r0.x * 64 + lane]), 0.f);
            float h1 = fmaxf(__half2float(hin[(long)r1.x * 64 + lane]), 0.f);
            float h2 = fmaxf(__half2float(hin[(long)r2.x * 64 + lane]), 0.f);
            float h3 = fmaxf(__half2float(hin[(long)r3.x * 64 + lane]), 0.f);
            acc += __int_as_float(r0.y) * h0;
            acc += __int_as_float(r1.y) * h1;
            acc += __int_as_float(r2.y) * h2;
            acc += __int_as_float(r3.y) * h3;
        }
        for (; e < e1; e++) {
            int2 r = csr[e];
            acc += __int_as_float(r.y) * fmaxf(__half2float(hin[(long)r.x * 64 + lane]), 0.f);
        }
        // wave-local LDS transpose: g row -> epilogue matvec (same wave, DS-ordered)
        gw[lane] = acc;
        __builtin_amdgcn_wave_barrier();
        float o = bl;
#pragma unroll
        for (int k = 0; k < 64; k++) o += gw[k] * Ws[k * 64 + lane];
        if (SIG) {
            o = 1.0f / (1.0f + expf(-o));
            ((float*)outp)[(long)n * 64 + lane] = o;
        } else {
            ((__half*)outp)[(long)n * 64 + lane] = __float2half(o);  // pre-relu
        }
        __builtin_amdgcn_wave_barrier();
    }
}

// ---------------- launch ----------------

extern "C" void kernel_launch(void* const* d_in, const int* in_sizes, int n_in,
                              void* d_out, int out_size, void* d_ws, size_t ws_size,
                              hipStream_t stream) {
    const float* x  = (const float*)d_in[0];
    const int*   ei = (const int*)  d_in[1];
    const float* ew = (const float*)d_in[2];
    const float* W0 = (const float*)d_in[3];
    const float* b0 = (const float*)d_in[4];
    const float* Wm = (const float*)d_in[5];
    const float* bm = (const float*)d_in[6];
    const float* Wl = (const float*)d_in[7];
    const float* bl = (const float*)d_in[8];
    float* out = (float*)d_out;

    const int* src = ei;
    const int* dst = ei + N_EDGES;

    char* ws = (char*)d_ws;
    unsigned long long* packed = (unsigned long long*)(ws + 0);        // 800 KB
    float*  dinv   = (float*)(ws + (1u  << 20));                        // 400 KB
    int*    rowptr = (int*)  (ws + (2u  << 20));                        // 400 KB
    int*    bsum   = (int*)  (ws + (3u  << 20));                        // 2 KB
    int*    ord    = (int*)  (ws + (3u  << 20) + 65536);                // 6.4 MB
    int2*   csr    = (int2*) (ws + (11u << 20));                        // 12.8 MB
    float*  htmp   = (float*)(ws + (24u << 20));                        // 25.6 MB
    __half* hA     = (__half*)(ws + (50u << 20));                       // 12.8 MB
    __half* hB     = (__half*)(ws + (63u << 20));                       // 12.8 MB

    const int BT = 256;
    dim3 blk(BT);
    int gN   = NB_NODES;                       // 391
    int gE   = (N_EDGES + BT - 1) / BT;        // 6250
    int gR4  = (N_NODES + 3) / 4;              // 25000 (gemm0)
    int gW   = (N_NODES * 64 + BT - 1) / BT;   // 25000 (gather0: 1 wave/node)
    int gWF  = N_NODES / 32;                   // 3125 (gather_w: 8 nodes/wave, exact)

    // prelude: packed count+degree, 3-phase scan, atomic-free CSR fill
    hipLaunchKernelGGL(k_initp,   dim3(gN), blk, 0, stream, packed);
    hipLaunchKernelGGL(k_cnt,     dim3(gE), blk, 0, stream, dst, ew, packed, ord);
    hipLaunchKernelGGL(k_part,    dim3(gN), blk, 0, stream, packed, bsum, dinv);
    hipLaunchKernelGGL(k_scanb,   dim3(1), dim3(512), 0, stream, bsum, rowptr);
    hipLaunchKernelGGL(k_fillptr, dim3(gN), blk, 0, stream, packed, bsum, rowptr);
    hipLaunchKernelGGL(k_fill,    dim3(gE), blk, 0, stream, src, dst, ew, dinv, rowptr, ord, csr);

    // layer 0: x W0 (fp32) then aggregate -> fp16
    hipLaunchKernelGGL(k_gemm0,   dim3(gR4), blk, 0, stream, x, W0, htmp);
    hipLaunchKernelGGL(k_gather0, dim3(gW),  blk, 0, stream, rowptr, csr, htmp, dinv, b0, hA);

    // middle layers 1..6: fused (A relu(h)) W + b, fp16 -> fp16
    __half* hin = hA;
    __half* hout = hB;
    for (int i = 0; i < 6; i++) {
        const float* Wi = Wm + (long)i * 64 * 64;
        const float* bi = bm + (long)i * 64;
        hipLaunchKernelGGL((k_gather_w<false>), dim3(gWF), blk, 0, stream,
                           rowptr, csr, hin, dinv, Wi, bi, (void*)hout);
        __half* t2 = hin; hin = hout; hout = t2;
    }

    // final layer: fused aggregate + W + bias + sigmoid -> fp32 d_out
    hipLaunchKernelGGL((k_gather_w<true>), dim3(gWF), blk, 0, stream,
                       rowptr, csr, hin, dinv, Wl, bl, (void*)out);
}